// Round 1
// baseline (434.190 us; speedup 1.0000x reference)
//
#include <hip/hip_runtime.h>
#include <hip/hip_cooperative_groups.h>
#include <math.h>

namespace cg = cooperative_groups;

#define B 64
#define S 512
#define H 768
#define U 16
#define C 5
#define M (B*U)          // 1024 segments

typedef __attribute__((ext_vector_type(8))) short short8;
typedef __attribute__((ext_vector_type(4))) float floatx4;

__device__ inline unsigned short f2bf(float x) {          // round-to-nearest-even
    unsigned u = __float_as_uint(x);
    u += 0x7FFFu + ((u >> 16) & 1u);
    return (unsigned short)(u >> 16);
}
__device__ inline float bf2f(unsigned short b) {
    return __uint_as_float((unsigned)b << 16);
}
__device__ inline void acc4(float4& a, const float4& v) {
    a.x += v.x; a.y += v.y; a.z += v.z; a.w += v.w;
}

// ---------------------------------------------------------------------------
// Single cooperative kernel, 1024 blocks x 192 threads (4 blocks/CU, trivially
// co-resident: 12 waves/CU, 4.2 KB LDS, VGPR capped by launch_bounds(192,3)).
//   phase 1a (all blocks):   per-(b,u) segment mean -> bf16 means
//   phase 1b (blocks <576):  Wh fp32 [K][N] -> Bt bf16 [N][K] via LDS transpose
//   --- grid.sync ---
//   phase 2  (blocks <256):  hbuf = bf16(selu(means @ Wh + bh)), 3 waves/block
//                            -> 768 wave-tiles of 32x32, 16x16x32 bf16 MFMA
//   --- grid.sync ---
//   phase 3  (rows = bi*3+wid < 1024): logits + softmax, one wave per row
// Removes two kernel launches + inter-kernel gaps vs the 3-kernel version.
// ---------------------------------------------------------------------------
__global__ __launch_bounds__(192, 3) void fused_kernel(
    const float* __restrict__ hidden, const int* __restrict__ seg,
    const float* __restrict__ Wh, const float* __restrict__ bh,
    const float* __restrict__ Wo, const float* __restrict__ bo,
    unsigned short* __restrict__ means, unsigned short* __restrict__ Bt,
    unsigned short* __restrict__ hbuf, float* __restrict__ out)
{
    cg::grid_group grid = cg::this_grid();
    __shared__ float tile[32][33];
    const int t  = threadIdx.x;
    const int bi = blockIdx.x;

    // ---- phase 1a: segment mean (verbatim from verified prep_kernel) ----
    {
        const int b = bi >> 4;     // U = 16
        const int u = bi & 15;
        const int* srow = seg + b * S;

        int lo = 0, hi = S;                // lower_bound(u)
        while (lo < hi) { int mid = (lo + hi) >> 1; if (srow[mid] < u) lo = mid + 1; else hi = mid; }
        const int start = lo;
        hi = S;                            // lower_bound(u+1)
        while (lo < hi) { int mid = (lo + hi) >> 1; if (srow[mid] < u + 1) lo = mid + 1; else hi = mid; }
        const int end = lo;

        const float4* h4 = (const float4*)(hidden + (size_t)b * S * H) + t;
        const int ldr = H / 4;

        float4 a0 = make_float4(0.f,0.f,0.f,0.f), a1 = a0, a2 = a0, a3 = a0;
        int s = start;
        #pragma unroll 2
        for (; s + 4 <= end; s += 4) {
            float4 v0 = h4[(size_t)(s + 0) * ldr];
            float4 v1 = h4[(size_t)(s + 1) * ldr];
            float4 v2 = h4[(size_t)(s + 2) * ldr];
            float4 v3 = h4[(size_t)(s + 3) * ldr];
            acc4(a0, v0); acc4(a1, v1); acc4(a2, v2); acc4(a3, v3);
        }
        for (; s < end; ++s) acc4(a0, h4[(size_t)s * ldr]);

        acc4(a0, a1); acc4(a2, a3); acc4(a0, a2);
        const float inv = 1.0f / fmaxf((float)(end - start), 1.0f);
        ushort4 o;
        o.x = f2bf(a0.x * inv); o.y = f2bf(a0.y * inv);
        o.z = f2bf(a0.z * inv); o.w = f2bf(a0.w * inv);
        ((ushort4*)(means + (size_t)bi * H))[t] = o;   // bi == b*U + u
    }

    // ---- phase 1b: Wh transpose + bf16 convert (blocks 0..575) ----
    if (bi < (H / 32) * (H / 32)) {
        const int bn = bi % (H / 32);
        const int bk = bi / (H / 32);
        #pragma unroll
        for (int i = 0; i < 6; ++i) {
            int idx = t + 192 * i;
            if (idx < 1024) {
                int r = idx >> 5, c = idx & 31;
                tile[r][c] = Wh[(size_t)(bk * 32 + r) * H + bn * 32 + c];
            }
        }
        __syncthreads();
        #pragma unroll
        for (int i = 0; i < 6; ++i) {
            int idx = t + 192 * i;
            if (idx < 1024) {
                int r = idx >> 5, c = idx & 31;   // r = n in tile, c = k in tile
                Bt[(size_t)(bn * 32 + r) * H + bk * 32 + c] = f2bf(tile[c][r]);
            }
        }
    }

    grid.sync();   // means + Bt visible device-wide

    const int wid  = t >> 6;
    const int lane = t & 63;

    // ---- phase 2: gemm1 (blocks 0..255, 3 waves each -> 768 tiles) ----
    if (bi < (M / 32) * (H / 32) / 3) {
        const int tileId = bi * 3 + wid;            // 0..767
        const int tm = tileId / (H / 32);           // 0..31
        const int tn = tileId % (H / 32);           // 0..23
        const int m0 = tm * 32, n0 = tn * 32;

        const int quad = lane >> 4;
        const int l16  = lane & 15;

        const short8* ap0 = (const short8*)(means + (size_t)(m0 + l16) * H);
        const short8* ap1 = (const short8*)(means + (size_t)(m0 + 16 + l16) * H);
        const short8* bp0 = (const short8*)(Bt    + (size_t)(n0 + l16) * H);
        const short8* bp1 = (const short8*)(Bt    + (size_t)(n0 + 16 + l16) * H);

        floatx4 acc00 = {0.f, 0.f, 0.f, 0.f}, acc01 = acc00, acc10 = acc00, acc11 = acc00;
        #pragma unroll 4
        for (int kk = 0; kk < H / 32; ++kk) {
            short8 a0 = ap0[4 * kk + quad];
            short8 a1 = ap1[4 * kk + quad];
            short8 b0 = bp0[4 * kk + quad];
            short8 b1 = bp1[4 * kk + quad];
            acc00 = __builtin_amdgcn_mfma_f32_16x16x32_bf16(a0, b0, acc00, 0, 0, 0);
            acc01 = __builtin_amdgcn_mfma_f32_16x16x32_bf16(a0, b1, acc01, 0, 0, 0);
            acc10 = __builtin_amdgcn_mfma_f32_16x16x32_bf16(a1, b0, acc10, 0, 0, 0);
            acc11 = __builtin_amdgcn_mfma_f32_16x16x32_bf16(a1, b1, acc11, 0, 0, 0);
        }

        const float SC = 1.0507009873554805f, AL = 1.6732632423543772f;
        const float bs0 = bh[n0 + l16], bs1 = bh[n0 + 16 + l16];
        #pragma unroll
        for (int r = 0; r < 4; ++r) {
            unsigned short* row0 = hbuf + (size_t)(m0 + quad * 4 + r) * H;
            unsigned short* row1 = hbuf + (size_t)(m0 + 16 + quad * 4 + r) * H;
            float x;
            x = acc00[r] + bs0; row0[n0 + l16]      = f2bf(x > 0.f ? SC * x : SC * AL * (expf(x) - 1.f));
            x = acc01[r] + bs1; row0[n0 + 16 + l16] = f2bf(x > 0.f ? SC * x : SC * AL * (expf(x) - 1.f));
            x = acc10[r] + bs0; row1[n0 + l16]      = f2bf(x > 0.f ? SC * x : SC * AL * (expf(x) - 1.f));
            x = acc11[r] + bs1; row1[n0 + 16 + l16] = f2bf(x > 0.f ? SC * x : SC * AL * (expf(x) - 1.f));
        }
    }

    grid.sync();   // hbuf visible device-wide

    // ---- phase 3: head, one wave per output row ----
    {
        const int row = bi * 3 + wid;
        if (row < M) {
            float acc[C] = {};
            #pragma unroll
            for (int j = 0; j < H / 128; ++j) {
                int k = 128 * j + 2 * lane;
                ushort2 hv = *(const ushort2*)(hbuf + (size_t)row * H + k);
                float h0 = bf2f(hv.x), h1 = bf2f(hv.y);
                #pragma unroll
                for (int cc = 0; cc < C; ++cc)
                    acc[cc] += h0 * Wo[(size_t)k * C + cc] + h1 * Wo[(size_t)(k + 1) * C + cc];
            }
            #pragma unroll
            for (int off = 32; off >= 1; off >>= 1)
                #pragma unroll
                for (int cc = 0; cc < C; ++cc) acc[cc] += __shfl_down(acc[cc], off);

            if (lane == 0) {
                float l[C], mx = -1e30f;
                #pragma unroll
                for (int cc = 0; cc < C; ++cc) { l[cc] = acc[cc] + bo[cc]; mx = fmaxf(mx, l[cc]); }
                float sum = 0.f;
                #pragma unroll
                for (int cc = 0; cc < C; ++cc) { l[cc] = expf(l[cc] - mx); sum += l[cc]; }
                float r = 1.0f / sum;
                #pragma unroll
                for (int cc = 0; cc < C; ++cc) out[(size_t)row * C + cc] = l[cc] * r;
            }
        }
    }
}

// ---------------------------------------------------------------------------
extern "C" void kernel_launch(void* const* d_in, const int* in_sizes, int n_in,
                              void* d_out, int out_size, void* d_ws, size_t ws_size,
                              hipStream_t stream)
{
    const float* hidden = (const float*)d_in[0];
    const int*   seg    = (const int*)d_in[1];
    const float* Wh = (const float*)d_in[3];
    const float* bh = (const float*)d_in[4];
    const float* Wo = (const float*)d_in[5];
    const float* bo = (const float*)d_in[6];
    float* out = (float*)d_out;

    unsigned short* means = (unsigned short*)d_ws;           // M*H bf16
    unsigned short* Bt    = means + (size_t)M * H;           // H*H bf16
    unsigned short* hbuf  = Bt + (size_t)H * H;              // M*H bf16

    void* args[] = { (void*)&hidden, (void*)&seg, (void*)&Wh, (void*)&bh,
                     (void*)&Wo, (void*)&bo, (void*)&means, (void*)&Bt,
                     (void*)&hbuf, (void*)&out };
    hipLaunchCooperativeKernel((void*)fused_kernel, dim3(M), dim3(192), args, 0, stream);
}

// Round 2
// 208.293 us; speedup vs baseline: 2.0845x; 2.0845x over previous
//
#include <hip/hip_runtime.h>
#include <math.h>

#define B 64
#define S 512
#define H 768
#define U 16
#define C 5
#define M (B*U)          // 1024 segments

typedef __attribute__((ext_vector_type(8))) short short8;
typedef __attribute__((ext_vector_type(4))) float floatx4;

__device__ inline unsigned short f2bf(float x) {          // round-to-nearest-even
    unsigned u = __float_as_uint(x);
    u += 0x7FFFu + ((u >> 16) & 1u);
    return (unsigned short)(u >> 16);
}
__device__ inline float bf2f(unsigned short b) {
    return __uint_as_float((unsigned)b << 16);
}
__device__ inline void acc4(float4& a, const float4& v) {
    a.x += v.x; a.y += v.y; a.z += v.z; a.w += v.w;
}

// ---------------------------------------------------------------------------
// Kernel 1 (verbatim from the 181 µs verified version):
//   blocks [0, M):      per-(b,u) segment mean -> bf16 means (binary search
//                       over the sorted seg row; 4-deep token unroll).
//   blocks [M, M+576):  Wh fp32 [K][N] -> Bt bf16 [N][K] via LDS transpose.
// ---------------------------------------------------------------------------
__global__ __launch_bounds__(192) void prep_kernel(
    const float* __restrict__ hidden, const int* __restrict__ seg,
    const float* __restrict__ Wh,
    unsigned short* __restrict__ means, unsigned short* __restrict__ Bt)
{
    __shared__ float tile[32][33];
    const int t = threadIdx.x;

    if (blockIdx.x < M) {
        // ---- segment mean ----
        const int b = blockIdx.x >> 4;     // U = 16
        const int u = blockIdx.x & 15;
        const int* srow = seg + b * S;

        int lo = 0, hi = S;                // lower_bound(u)
        while (lo < hi) { int mid = (lo + hi) >> 1; if (srow[mid] < u) lo = mid + 1; else hi = mid; }
        const int start = lo;
        hi = S;                            // lower_bound(u+1)
        while (lo < hi) { int mid = (lo + hi) >> 1; if (srow[mid] < u + 1) lo = mid + 1; else hi = mid; }
        const int end = lo;

        const float4* h4 = (const float4*)(hidden + (size_t)b * S * H) + t;
        const int ldr = H / 4;

        float4 a0 = make_float4(0.f,0.f,0.f,0.f), a1 = a0, a2 = a0, a3 = a0;
        int s = start;
        #pragma unroll 2
        for (; s + 4 <= end; s += 4) {
            float4 v0 = h4[(size_t)(s + 0) * ldr];
            float4 v1 = h4[(size_t)(s + 1) * ldr];
            float4 v2 = h4[(size_t)(s + 2) * ldr];
            float4 v3 = h4[(size_t)(s + 3) * ldr];
            acc4(a0, v0); acc4(a1, v1); acc4(a2, v2); acc4(a3, v3);
        }
        for (; s < end; ++s) acc4(a0, h4[(size_t)s * ldr]);

        acc4(a0, a1); acc4(a2, a3); acc4(a0, a2);
        const float inv = 1.0f / fmaxf((float)(end - start), 1.0f);
        ushort4 o;
        o.x = f2bf(a0.x * inv); o.y = f2bf(a0.y * inv);
        o.z = f2bf(a0.z * inv); o.w = f2bf(a0.w * inv);
        ((ushort4*)(means + (size_t)(b * U + u) * H))[t] = o;
        return;
    }

    // ---- Wh transpose + bf16 convert ----
    const int tb = blockIdx.x - M;          // 0..575
    const int bn = tb % (H / 32);
    const int bk = tb / (H / 32);
    #pragma unroll
    for (int i = 0; i < 6; ++i) {
        int idx = t + 192 * i;
        if (idx < 1024) {
            int r = idx >> 5, c = idx & 31;
            tile[r][c] = Wh[(size_t)(bk * 32 + r) * H + bn * 32 + c];
        }
    }
    __syncthreads();
    #pragma unroll
    for (int i = 0; i < 6; ++i) {
        int idx = t + 192 * i;
        if (idx < 1024) {
            int r = idx >> 5, c = idx & 31;   // r = n in tile, c = k in tile
            Bt[(size_t)(bn * 32 + r) * H + bk * 32 + c] = f2bf(tile[c][r]);
        }
    }
}

// ---------------------------------------------------------------------------
// Kernel 2: fused gemm1 + head. 64 blocks x 512 threads (8 waves).
// Block bi owns output rows m0..m0+15 (m0 = 16*bi). Wave w computes the
// 16 x 96 strip at columns [96w, 96w+96): 6 MFMA tiles of 16x16, K=768,
// A-frag shared across the 6 B-frags per k-step (fragment indexing copied
// from the verified gemm1). SELU epilogue lands in LDS as bf16
// (row pad +4 bf16 -> quad rows 8 banks apart, 2-way conflict = free).
// After one __syncthreads, wave w finishes rows 2w, 2w+1: 5-col GEMV from
// LDS + shuffle reduce + softmax. Saves one kernel launch and the hbuf
// global round-trip vs the 3-kernel version.
// ---------------------------------------------------------------------------
__global__ __launch_bounds__(512) void gemm_head_kernel(
    const unsigned short* __restrict__ means, const unsigned short* __restrict__ Bt,
    const float* __restrict__ bh, const float* __restrict__ Wo,
    const float* __restrict__ bo, float* __restrict__ out)
{
    __shared__ unsigned short hl[16][H + 4];   // 16 x 772 bf16 = 24.7 KB

    const int wid  = threadIdx.x >> 6;
    const int lane = threadIdx.x & 63;
    const int quad = lane >> 4;
    const int l16  = lane & 15;
    const int m0   = blockIdx.x * 16;
    const int nb   = wid * 96;                 // wave's column base

    const short8* ap = (const short8*)(means + (size_t)(m0 + l16) * H);
    const short8* bp[6];
    #pragma unroll
    for (int tt = 0; tt < 6; ++tt)
        bp[tt] = (const short8*)(Bt + (size_t)(nb + tt * 16 + l16) * H);

    floatx4 acc[6];
    #pragma unroll
    for (int tt = 0; tt < 6; ++tt) acc[tt] = (floatx4){0.f, 0.f, 0.f, 0.f};

    #pragma unroll 2
    for (int kk = 0; kk < H / 32; ++kk) {
        short8 a = ap[4 * kk + quad];
        #pragma unroll
        for (int tt = 0; tt < 6; ++tt) {
            short8 b = bp[tt][4 * kk + quad];
            acc[tt] = __builtin_amdgcn_mfma_f32_16x16x32_bf16(a, b, acc[tt], 0, 0, 0);
        }
    }

    // ---- SELU epilogue -> LDS ----
    const float SC = 1.0507009873554805f, AL = 1.6732632423543772f;
    #pragma unroll
    for (int tt = 0; tt < 6; ++tt) {
        const float bs = bh[nb + tt * 16 + l16];
        #pragma unroll
        for (int r = 0; r < 4; ++r) {
            float x = acc[tt][r] + bs;
            hl[quad * 4 + r][nb + tt * 16 + l16] =
                f2bf(x > 0.f ? SC * x : SC * AL * (expf(x) - 1.f));
        }
    }

    __syncthreads();

    // ---- head: wave w handles rows 2w, 2w+1 ----
    #pragma unroll
    for (int rr2 = 0; rr2 < 2; ++rr2) {
        const int rr = wid * 2 + rr2;
        float acc2[C] = {};
        #pragma unroll
        for (int j = 0; j < H / 128; ++j) {
            int k = 128 * j + 2 * lane;
            ushort2 hv = *(const ushort2*)(&hl[rr][k]);
            float h0 = bf2f(hv.x), h1 = bf2f(hv.y);
            #pragma unroll
            for (int cc = 0; cc < C; ++cc)
                acc2[cc] += h0 * Wo[(size_t)k * C + cc] + h1 * Wo[(size_t)(k + 1) * C + cc];
        }
        #pragma unroll
        for (int off = 32; off >= 1; off >>= 1)
            #pragma unroll
            for (int cc = 0; cc < C; ++cc) acc2[cc] += __shfl_down(acc2[cc], off);

        if (lane == 0) {
            float l[C], mx = -1e30f;
            #pragma unroll
            for (int cc = 0; cc < C; ++cc) { l[cc] = acc2[cc] + bo[cc]; mx = fmaxf(mx, l[cc]); }
            float sum = 0.f;
            #pragma unroll
            for (int cc = 0; cc < C; ++cc) { l[cc] = expf(l[cc] - mx); sum += l[cc]; }
            float r = 1.0f / sum;
            #pragma unroll
            for (int cc = 0; cc < C; ++cc) out[(size_t)(m0 + rr) * C + cc] = l[cc] * r;
        }
    }
}

// ---------------------------------------------------------------------------
extern "C" void kernel_launch(void* const* d_in, const int* in_sizes, int n_in,
                              void* d_out, int out_size, void* d_ws, size_t ws_size,
                              hipStream_t stream)
{
    const float* hidden = (const float*)d_in[0];
    const int*   seg    = (const int*)d_in[1];
    const float* Wh = (const float*)d_in[3];
    const float* bh = (const float*)d_in[4];
    const float* Wo = (const float*)d_in[5];
    const float* bo = (const float*)d_in[6];
    float* out = (float*)d_out;

    unsigned short* means = (unsigned short*)d_ws;           // M*H bf16
    unsigned short* Bt    = means + (size_t)M * H;           // H*H bf16

    prep_kernel<<<M + (H / 32) * (H / 32), 192, 0, stream>>>(hidden, seg, Wh, means, Bt);
    gemm_head_kernel<<<M / 16, 512, 0, stream>>>(means, Bt, bh, Wo, bo, out);
}

// Round 3
// 169.569 us; speedup vs baseline: 2.5605x; 1.2284x over previous
//
#include <hip/hip_runtime.h>
#include <math.h>

#define B 64
#define S 512
#define H 768
#define U 16
#define C 5
#define M (B*U)          // 1024 segments

typedef __attribute__((ext_vector_type(8))) short short8;
typedef __attribute__((ext_vector_type(4))) float floatx4;

__device__ inline unsigned short f2bf(float x) {          // round-to-nearest-even
    unsigned u = __float_as_uint(x);
    u += 0x7FFFu + ((u >> 16) & 1u);
    return (unsigned short)(u >> 16);
}
__device__ inline float bf2f(unsigned short b) {
    return __uint_as_float((unsigned)b << 16);
}

// ---------------------------------------------------------------------------
// Kernel 1 (fused prep, independent work in one grid to save a launch gap):
//   blocks [0, M):      per-(b,u) segment mean -> bf16 means (binary search
//                       over the sorted seg row; 4-deep token unroll).
//   blocks [M, M+576):  Wh fp32 [K][N] -> Bt bf16 [N][K] via LDS transpose.
// hidden is streamed once with no reuse -> non-temporal loads (nt) keep it
// out of L2/L3 so Wh/means/Bt lines stay hot for gemm1.
// ---------------------------------------------------------------------------
__global__ __launch_bounds__(192) void prep_kernel(
    const float* __restrict__ hidden, const int* __restrict__ seg,
    const float* __restrict__ Wh,
    unsigned short* __restrict__ means, unsigned short* __restrict__ Bt)
{
    __shared__ float tile[32][33];
    const int t = threadIdx.x;

    if (blockIdx.x < M) {
        // ---- segment mean ----
        const int b = blockIdx.x >> 4;     // U = 16
        const int u = blockIdx.x & 15;
        const int* srow = seg + b * S;

        int lo = 0, hi = S;                // lower_bound(u)
        while (lo < hi) { int mid = (lo + hi) >> 1; if (srow[mid] < u) lo = mid + 1; else hi = mid; }
        const int start = lo;
        hi = S;                            // lower_bound(u+1)
        while (lo < hi) { int mid = (lo + hi) >> 1; if (srow[mid] < u + 1) lo = mid + 1; else hi = mid; }
        const int end = lo;

        const floatx4* h4 = (const floatx4*)(hidden + (size_t)b * S * H) + t;
        const int ldr = H / 4;

        floatx4 a0 = {0.f, 0.f, 0.f, 0.f}, a1 = a0, a2 = a0, a3 = a0;
        int s = start;
        #pragma unroll 2
        for (; s + 4 <= end; s += 4) {
            floatx4 v0 = __builtin_nontemporal_load(&h4[(size_t)(s + 0) * ldr]);
            floatx4 v1 = __builtin_nontemporal_load(&h4[(size_t)(s + 1) * ldr]);
            floatx4 v2 = __builtin_nontemporal_load(&h4[(size_t)(s + 2) * ldr]);
            floatx4 v3 = __builtin_nontemporal_load(&h4[(size_t)(s + 3) * ldr]);
            a0 += v0; a1 += v1; a2 += v2; a3 += v3;
        }
        for (; s < end; ++s) a0 += __builtin_nontemporal_load(&h4[(size_t)s * ldr]);

        a0 += a1; a2 += a3; a0 += a2;
        const float inv = 1.0f / fmaxf((float)(end - start), 1.0f);
        ushort4 o;
        o.x = f2bf(a0.x * inv); o.y = f2bf(a0.y * inv);
        o.z = f2bf(a0.z * inv); o.w = f2bf(a0.w * inv);
        ((ushort4*)(means + (size_t)(b * U + u) * H))[t] = o;
        return;
    }

    // ---- Wh transpose + bf16 convert ----
    const int tb = blockIdx.x - M;          // 0..575
    const int bn = tb % (H / 32);
    const int bk = tb / (H / 32);
    #pragma unroll
    for (int i = 0; i < 6; ++i) {
        int idx = t + 192 * i;
        if (idx < 1024) {
            int r = idx >> 5, c = idx & 31;
            tile[r][c] = Wh[(size_t)(bk * 32 + r) * H + bn * 32 + c];
        }
    }
    __syncthreads();
    #pragma unroll
    for (int i = 0; i < 6; ++i) {
        int idx = t + 192 * i;
        if (idx < 1024) {
            int r = idx >> 5, c = idx & 31;   // r = n in tile, c = k in tile
            Bt[(size_t)(bn * 32 + r) * H + bk * 32 + c] = f2bf(tile[c][r]);
        }
    }
}

// ---------------------------------------------------------------------------
// Kernel 2: hbuf = bf16(selu(means @ Wh + bh)), bf16 MFMA 16x16x32, fp32 acc.
// Wave owns a 32m x 32n tile: 2 A-frags x 2 B-frags -> 4 MFMAs per k-step,
// 1:1 load:MFMA. 768 waves = 192 blocks. bf16 store halves hbuf traffic.
// ---------------------------------------------------------------------------
__global__ __launch_bounds__(256) void gemm1_mfma_kernel(
    const unsigned short* __restrict__ means, const unsigned short* __restrict__ Bt,
    const float* __restrict__ bh, unsigned short* __restrict__ hout)
{
    const int wid  = threadIdx.x >> 6;
    const int lane = threadIdx.x & 63;
    const int tile = blockIdx.x * 4 + wid;      // 0..767
    const int tm = tile / (H / 32);             // 0..31
    const int tn = tile % (H / 32);             // 0..23
    const int m0 = tm * 32, n0 = tn * 32;

    const int quad = lane >> 4;
    const int l16  = lane & 15;

    const short8* ap0 = (const short8*)(means + (size_t)(m0 + l16) * H);
    const short8* ap1 = (const short8*)(means + (size_t)(m0 + 16 + l16) * H);
    const short8* bp0 = (const short8*)(Bt    + (size_t)(n0 + l16) * H);
    const short8* bp1 = (const short8*)(Bt    + (size_t)(n0 + 16 + l16) * H);

    floatx4 acc00 = {0.f, 0.f, 0.f, 0.f}, acc01 = acc00, acc10 = acc00, acc11 = acc00;
    #pragma unroll 4
    for (int kk = 0; kk < H / 32; ++kk) {
        short8 a0 = ap0[4 * kk + quad];
        short8 a1 = ap1[4 * kk + quad];
        short8 b0 = bp0[4 * kk + quad];
        short8 b1 = bp1[4 * kk + quad];
        acc00 = __builtin_amdgcn_mfma_f32_16x16x32_bf16(a0, b0, acc00, 0, 0, 0);
        acc01 = __builtin_amdgcn_mfma_f32_16x16x32_bf16(a0, b1, acc01, 0, 0, 0);
        acc10 = __builtin_amdgcn_mfma_f32_16x16x32_bf16(a1, b0, acc10, 0, 0, 0);
        acc11 = __builtin_amdgcn_mfma_f32_16x16x32_bf16(a1, b1, acc11, 0, 0, 0);
    }

    const float SC = 1.0507009873554805f, AL = 1.6732632423543772f;
    const float bs0 = bh[n0 + l16], bs1 = bh[n0 + 16 + l16];
    #pragma unroll
    for (int r = 0; r < 4; ++r) {
        unsigned short* row0 = hout + (size_t)(m0 + quad * 4 + r) * H;
        unsigned short* row1 = hout + (size_t)(m0 + 16 + quad * 4 + r) * H;
        float x;
        x = acc00[r] + bs0; row0[n0 + l16]      = f2bf(x > 0.f ? SC * x : SC * AL * (expf(x) - 1.f));
        x = acc01[r] + bs1; row0[n0 + 16 + l16] = f2bf(x > 0.f ? SC * x : SC * AL * (expf(x) - 1.f));
        x = acc10[r] + bs0; row1[n0 + l16]      = f2bf(x > 0.f ? SC * x : SC * AL * (expf(x) - 1.f));
        x = acc11[r] + bs1; row1[n0 + 16 + l16] = f2bf(x > 0.f ? SC * x : SC * AL * (expf(x) - 1.f));
    }
}

// ---------------------------------------------------------------------------
// Kernel 3: logits = h @ Wo + bo, softmax over C=5. One wave per row;
// ushort2 (2 x bf16) loads per lane.
// ---------------------------------------------------------------------------
__global__ __launch_bounds__(256) void head_kernel(
    const unsigned short* __restrict__ hbuf, const float* __restrict__ Wo,
    const float* __restrict__ bo, float* __restrict__ out)
{
    const int wave = threadIdx.x >> 6;
    const int lane = threadIdx.x & 63;
    const int row  = blockIdx.x * 4 + wave;

    float acc[C] = {};
    #pragma unroll
    for (int j = 0; j < H / 128; ++j) {
        int k = 128 * j + 2 * lane;
        ushort2 hv = *(const ushort2*)(hbuf + (size_t)row * H + k);
        float h0 = bf2f(hv.x), h1 = bf2f(hv.y);
        #pragma unroll
        for (int cc = 0; cc < C; ++cc)
            acc[cc] += h0 * Wo[(size_t)k * C + cc] + h1 * Wo[(size_t)(k + 1) * C + cc];
    }
    #pragma unroll
    for (int off = 32; off >= 1; off >>= 1)
        #pragma unroll
        for (int cc = 0; cc < C; ++cc) acc[cc] += __shfl_down(acc[cc], off);

    if (lane == 0) {
        float l[C], mx = -1e30f;
        #pragma unroll
        for (int cc = 0; cc < C; ++cc) { l[cc] = acc[cc] + bo[cc]; mx = fmaxf(mx, l[cc]); }
        float sum = 0.f;
        #pragma unroll
        for (int cc = 0; cc < C; ++cc) { l[cc] = expf(l[cc] - mx); sum += l[cc]; }
        float r = 1.0f / sum;
        #pragma unroll
        for (int cc = 0; cc < C; ++cc) out[(size_t)row * C + cc] = l[cc] * r;
    }
}

// ---------------------------------------------------------------------------
extern "C" void kernel_launch(void* const* d_in, const int* in_sizes, int n_in,
                              void* d_out, int out_size, void* d_ws, size_t ws_size,
                              hipStream_t stream)
{
    const float* hidden = (const float*)d_in[0];
    const int*   seg    = (const int*)d_in[1];
    const float* Wh = (const float*)d_in[3];
    const float* bh = (const float*)d_in[4];
    const float* Wo = (const float*)d_in[5];
    const float* bo = (const float*)d_in[6];
    float* out = (float*)d_out;

    unsigned short* means = (unsigned short*)d_ws;           // M*H bf16
    unsigned short* Bt    = means + (size_t)M * H;           // H*H bf16
    unsigned short* hbuf  = Bt + (size_t)H * H;              // M*H bf16

    prep_kernel<<<M + (H / 32) * (H / 32), 192, 0, stream>>>(hidden, seg, Wh, means, Bt);
    gemm1_mfma_kernel<<<(M / 32) * (H / 32) / 4, 256, 0, stream>>>(means, Bt, bh, hbuf);
    head_kernel<<<M / 4, 256, 0, stream>>>(hbuf, Wo, bo, out);
}